// Round 9
// baseline (90.445 us; speedup 1.0000x reference)
//
#include <hip/hip_runtime.h>
#include <hip/hip_bf16.h>
#include <math.h>

// Problem constants
constexpr int B_ = 4;
constexpr int N_ = 2048;
constexpr int D_ = 128;
constexpr int H_ = 4;
constexpr int E_ = 32768;
constexpr int W_ = 8;
constexpr int OUT_ = 128;
constexpr int HD_ = H_ * D_;    // 512
constexpr int C3_ = 3 * HD_;    // 1536 combined QKV cols
constexpr int CAP = 64;         // max edges per row bucket (Poisson(16))
constexpr int M_ = B_ * N_;     // 8192 rows

typedef __attribute__((ext_vector_type(8))) __bf16 bf16x8;
typedef __attribute__((ext_vector_type(4))) float f32x4;
typedef unsigned int uint32;
typedef unsigned short u16;

__device__ __forceinline__ u16 f2b(float f) {
    __hip_bfloat16 h = __float2bfloat16(f);
    return *(u16*)&h;
}
__device__ __forceinline__ float blo(uint32 u) { return __uint_as_float(u << 16); }
__device__ __forceinline__ float bhi(uint32 u) { return __uint_as_float(u & 0xffff0000u); }

// load 8 consecutive f32 and round to a bf16x8 MFMA fragment (RTNE)
__device__ __forceinline__ bf16x8 ldcvt8(const float* __restrict__ p) {
    const float4 f0 = *(const float4*)p;
    const float4 f1 = *(const float4*)(p + 4);
    union { u16 u[8]; bf16x8 v; } cv;
    cv.u[0]=f2b(f0.x); cv.u[1]=f2b(f0.y); cv.u[2]=f2b(f0.z); cv.u[3]=f2b(f0.w);
    cv.u[4]=f2b(f1.x); cv.u[5]=f2b(f1.y); cv.u[6]=f2b(f1.z); cv.u[7]=f2b(f1.w);
    return cv.v;
}

// async 16B global->LDS copy (dest = wave-uniform base + lane*16)
__device__ __forceinline__ void g2l16(const void* g, void* l) {
    __builtin_amdgcn_global_load_lds(
        (const __attribute__((address_space(1))) unsigned int*)(uintptr_t)g,
        (__attribute__((address_space(3))) unsigned int*)(uintptr_t)l,
        16, 0, 0);
}

// ---------------------------------------------------------------------------
// qkv_append: three block ranges, no staging buffers.
// [0,768):      QKV GEMM, A/B fragments loaded f32-direct + in-reg bf16 cast;
//               32KB LDS only for C repack; V col-blocks reduce vsum.
// [768,4864):   edge append (8 edges/wave, fully parallel).
// [4864,4896):  cast out_w -> OWbf (swizzled, for out_mfma's g2l16 path).
// ---------------------------------------------------------------------------
__global__ __launch_bounds__(256) void qkv_append(
    const float* __restrict__ X,
    const float* __restrict__ wq, const float* __restrict__ wk, const float* __restrict__ wv,
    const float* __restrict__ bq, const float* __restrict__ bk, const float* __restrict__ bv,
    const float* __restrict__ OW,
    const int* __restrict__ nidx, const float* __restrict__ attr,
    u16* __restrict__ QKV, float* __restrict__ vsum,
    int* __restrict__ row_count, int2* __restrict__ row_edges,
    u16* __restrict__ OWbf)
{
    __shared__ u16 Cs[128 * 128];          // 32KB (repack only)
    const int t = threadIdx.x;
    const int lane = t & 63, wave = t >> 6;

    if (blockIdx.x >= 4864) {              // ---- cast_ow path ----
        const int tid = (blockIdx.x - 4864) * 256 + t;   // 0..8191
        const int c = tid >> 6, sub = tid & 63;
        const float4 f0 = *(const float4*)(OW + (size_t)c * 512 + sub * 8);
        const float4 f1 = *(const float4*)(OW + (size_t)c * 512 + sub * 8 + 4);
        union { u16 u[8]; uint4 v; } pk;
        pk.u[0]=f2b(f0.x); pk.u[1]=f2b(f0.y); pk.u[2]=f2b(f0.z); pk.u[3]=f2b(f0.w);
        pk.u[4]=f2b(f1.x); pk.u[5]=f2b(f1.y); pk.u[6]=f2b(f1.z); pk.u[7]=f2b(f1.w);
        const int ob = c * 1024 + ((sub * 16) ^ ((c & 7) << 4));
        *(uint4*)((char*)OWbf + ob) = pk.v;
        return;
    }

    if (blockIdx.x >= 768) {               // ---- append path (no LDS use) ----
        const int gw = (blockIdx.x - 768) * 4 + wave;    // 0..16383
        const int e0g = gw * 8;
        const int b = e0g / E_;
        const int e0 = e0g % E_;
        float a = attr[((size_t)b * E_ + e0) * W_ + lane];
        a += __shfl_xor(a, 1);
        a += __shfl_xor(a, 2);
        a += __shfl_xor(a, 4);
        if ((lane & 7) == 0) {
            const int sub = lane >> 3;
            const int e = e0 + sub;
            const int i = nidx[b * 2 * E_ + e];
            const int j = nidx[b * 2 * E_ + E_ + e];
            const int pos = atomicAdd(&row_count[b * N_ + i], 1);
            if (pos < CAP)
                row_edges[(size_t)(b * N_ + i) * CAP + pos] =
                    make_int2(e | (j << 16), __float_as_int(a));
        }
        return;
    }

    // ---- gemm path ----
    const int rb = blockIdx.x & 63;
    const int g  = blockIdx.x >> 6;
    const int t3 = g >> 2, h = g & 3;
    const int wm = wave >> 1, wn = wave & 1;
    const int l15 = lane & 15, l4 = lane >> 4;

    const float* Abase = X + (size_t)(rb * 128) * 128;
    const float* Bbase = (t3 == 0 ? wq : t3 == 1 ? wk : wv) + (size_t)h * 128 * 128;
    const float* bsrc  = (t3 == 0 ? bq : t3 == 1 ? bk : bv) + h * 128;

    f32x4 acc[4][4];
    #pragma unroll
    for (int i = 0; i < 4; ++i)
        #pragma unroll
        for (int j = 0; j < 4; ++j) acc[i][j] = (f32x4){0.f, 0.f, 0.f, 0.f};

    #pragma unroll
    for (int ks = 0; ks < 4; ++ks) {
        const int ko = ks * 32 + l4 * 8;
        bf16x8 a[4], bb[4];
        #pragma unroll
        for (int fm = 0; fm < 4; ++fm)
            a[fm] = ldcvt8(Abase + (size_t)(wm * 64 + fm * 16 + l15) * 128 + ko);
        #pragma unroll
        for (int fn = 0; fn < 4; ++fn)
            bb[fn] = ldcvt8(Bbase + (size_t)(wn * 64 + fn * 16 + l15) * 128 + ko);
        #pragma unroll
        for (int fm = 0; fm < 4; ++fm)
            #pragma unroll
            for (int fn = 0; fn < 4; ++fn)
                acc[fm][fn] = __builtin_amdgcn_mfma_f32_16x16x32_bf16(
                    a[fm], bb[fn], acc[fm][fn], 0, 0, 0);
    }

    // write acc (+bias) into Cs as swizzled bf16 [row][256B]
    #pragma unroll
    for (int fm = 0; fm < 4; ++fm)
        #pragma unroll
        for (int fn = 0; fn < 4; ++fn) {
            const int col = wn * 64 + fn * 16 + l15;
            const float bv = bsrc[col];
            #pragma unroll
            for (int r = 0; r < 4; ++r) {
                const int row = wm * 64 + fm * 16 + l4 * 4 + r;
                *(u16*)((char*)Cs + row * 256 + ((col * 2) ^ ((row & 7) << 4))) =
                    f2b(acc[fm][fn][r] + bv);
            }
        }

    if (g >= 8) {   // fused V column-sum (includes bias via +64*bv per wave)
        const int b = rb >> 4;      // 16 row-blocks per batch
        #pragma unroll
        for (int fn = 0; fn < 4; ++fn) {
            float s = 0.f;
            #pragma unroll
            for (int fm = 0; fm < 4; ++fm)
                #pragma unroll
                for (int r = 0; r < 4; ++r) s += acc[fm][fn][r];
            s += __shfl_xor(s, 16);
            s += __shfl_xor(s, 32);
            if (l4 == 0) {
                const int col = wn * 64 + fn * 16 + l15;
                atomicAdd(&vsum[(b * H_ + h) * 128 + col], s + 64.f * bsrc[col]);
            }
        }
    }
    __syncthreads();

    // coalesced store: 8 x uint4 per thread
    #pragma unroll
    for (int q = 0; q < 8; ++q) {
        const int idx = t + q * 256;          // chunk 0..2047
        const int row = idx >> 4, c = idx & 15;
        const uint4 v = *(const uint4*)((char*)Cs + row * 256 + ((c * 16) ^ ((row & 7) << 4)));
        *(uint4*)(QKV + (size_t)(rb * 128 + row) * C3_ + g * 128 + c * 8) = v;
    }
}

// ---------------------------------------------------------------------------
// row_fused: wave-per-row scoring + sparse softmax + PV (dual accumulator
// chains + pair prefetch), XCD-pinned batch mapping: xcd = blockIdx.x & 7
// (round-robin dispatch); batch = xcd>>1 so each XCD's 4MB L2 holds exactly
// one batch's K+V slab.
// ---------------------------------------------------------------------------
__global__ __launch_bounds__(256) void row_fused(
    const u16* __restrict__ QKV, const float* __restrict__ vsum,
    const int* __restrict__ row_count, const int2* __restrict__ row_edges,
    u16* __restrict__ Obf)
{
    const int t = threadIdx.x;
    const int wave = t >> 6, lane = t & 63;
    const int gid = blockIdx.x;                 // 0..2047
    const int xcd = gid & 7;
    const int b = xcd >> 1;                     // 2 XCDs per batch
    const int rowgrp = ((xcd & 1) << 8) | (gid >> 3);   // 0..511
    const int row = rowgrp * 4 + wave;
    const int R = b * N_ + row;
    int cnt = row_count[R];
    if (cnt > CAP) cnt = CAP;

    // edge entries register-resident: lane p < cnt holds entry p
    int ej = 0; float ws = 0.f;
    if (lane < cnt) {
        const int2 v = row_edges[(size_t)R * CAP + lane];
        ej = v.x; ws = __int_as_float(v.y);
    }
    // last-e-wins dedup via shfl broadcast (winner = max e per j)
    const int myj = ej >> 16, mye = ej & 0xFFFF;
    bool win = (lane < cnt);
    for (int p = 0; p < cnt; ++p) {
        const int oj = __shfl(ej, p);
        if (win && (oj >> 16) == myj && (oj & 0xFFFF) > mye) win = false;
    }
    unsigned long long m = __ballot(win);

    const char* base = (const char*)QKV;
    const uint4 qv = *(const uint4*)(base + (size_t)R * 3072 + lane * 16);
    const float q0=blo(qv.x), q1=bhi(qv.x), q2=blo(qv.y), q3=bhi(qv.y),
                q4=blo(qv.z), q5=bhi(qv.z), q6=blo(qv.w), q7=bhi(qv.w);
    const float rs = 0.02209708691207961f;   // 1/sqrt(2048)

    float A0=0.f,A1=0.f,A2=0.f,A3=0.f,A4=0.f,A5=0.f,A6=0.f,A7=0.f;
    float B0=0.f,B1=0.f,B2=0.f,B3=0.f,B4=0.f,B5=0.f,B6=0.f,B7=0.f;
    float dsA = 0.f, dsB = 0.f;

#define FETCH(MM, KV1,VV1,W1,KV2,VV2,W2,NN)                                  \
    { int p_ = (int)__ffsll((long long)MM) - 1; MM &= MM - 1;                \
      const int j_ = __shfl(ej, p_) >> 16; W1 = __shfl(ws, p_);              \
      const char* nb_ = base + (size_t)(b * N_ + j_) * 3072;                 \
      KV1 = *(const uint4*)(nb_ + 1024 + lane * 16);                         \
      VV1 = *(const uint4*)(nb_ + 2048 + lane * 16);                         \
      if (MM) {                                                              \
        int q_ = (int)__ffsll((long long)MM) - 1; MM &= MM - 1;              \
        const int j2_ = __shfl(ej, q_) >> 16; W2 = __shfl(ws, q_);           \
        const char* nb2_ = base + (size_t)(b * N_ + j2_) * 3072;             \
        KV2 = *(const uint4*)(nb2_ + 1024 + lane * 16);                      \
        VV2 = *(const uint4*)(nb2_ + 2048 + lane * 16);                      \
        NN = 2;                                                              \
      } else NN = 1; }

#define PROC(kv, vv, wsp, S)                                                 \
    { float s_ = q0*blo(kv.x) + q1*bhi(kv.x) + q2*blo(kv.y) + q3*bhi(kv.y)   \
               + q4*blo(kv.z) + q5*bhi(kv.z) + q6*blo(kv.w) + q7*bhi(kv.w);  \
      s_ += __shfl_xor(s_, 1);                                               \
      s_ += __shfl_xor(s_, 2);                                               \
      s_ += __shfl_xor(s_, 4);                                               \
      s_ += __shfl_xor(s_, 8);                                               \
      const float x_ = expf(s_ * rs * (wsp)) - 1.f;                          \
      ds##S += x_;                                                           \
      S##0 = fmaf(x_, blo(vv.x), S##0); S##1 = fmaf(x_, bhi(vv.x), S##1);    \
      S##2 = fmaf(x_, blo(vv.y), S##2); S##3 = fmaf(x_, bhi(vv.y), S##3);    \
      S##4 = fmaf(x_, blo(vv.z), S##4); S##5 = fmaf(x_, bhi(vv.z), S##5);    \
      S##6 = fmaf(x_, blo(vv.w), S##6); S##7 = fmaf(x_, bhi(vv.w), S##7); }

    if (m) {
        uint4 kv1, vv1, kv2, vv2; float w1, w2; int n1;
        FETCH(m, kv1, vv1, w1, kv2, vv2, w2, n1);
        while (m) {
            uint4 nk1, nv1, nk2, nv2; float nw1, nw2; int n2;
            FETCH(m, nk1, nv1, nw1, nk2, nv2, nw2, n2);
            PROC(kv1, vv1, w1, A);
            if (n1 == 2) PROC(kv2, vv2, w2, B);
            kv1 = nk1; vv1 = nv1; w1 = nw1;
            kv2 = nk2; vv2 = nv2; w2 = nw2; n1 = n2;
        }
        PROC(kv1, vv1, w1, A);
        if (n1 == 2) PROC(kv2, vv2, w2, B);
    }
#undef FETCH
#undef PROC

    const float inv = 1.0f / (2048.0f + dsA + dsB);
    const float* vsp = vsum + (b * H_ + (lane >> 4)) * 128 + (lane & 15) * 8;
    const float4 vs0 = *(const float4*)vsp;
    const float4 vs1 = *(const float4*)(vsp + 4);
    union { u16 u[8]; uint4 v; } o;
    o.u[0]=f2b((vs0.x+A0+B0)*inv); o.u[1]=f2b((vs0.y+A1+B1)*inv);
    o.u[2]=f2b((vs0.z+A2+B2)*inv); o.u[3]=f2b((vs0.w+A3+B3)*inv);
    o.u[4]=f2b((vs1.x+A4+B4)*inv); o.u[5]=f2b((vs1.y+A5+B5)*inv);
    o.u[6]=f2b((vs1.z+A6+B6)*inv); o.u[7]=f2b((vs1.w+A7+B7)*inv);
    const int ob = ((lane >> 4) << 8) + (((lane & 15) * 16) ^ ((R & 7) << 4));
    *(uint4*)((char*)Obf + (size_t)R * 1024 + ob) = o.v;
}

// ---------------------------------------------------------------------------
// out_mfma: d_out[8192][128] f32 = Obf[8192][512] x OWbf[128][512]^T + out_b
// grid = 256 row-blocks (M-tile 32), 4 waves (2x2), wave tile 16x64.
// ---------------------------------------------------------------------------
__global__ __launch_bounds__(256) void out_mfma(
    const u16* __restrict__ Obf, const u16* __restrict__ OWbf,
    const float* __restrict__ bo, float* __restrict__ Out)
{
    __shared__ u16 As[32 * 128];    // 8KB
    __shared__ u16 Bs[128 * 128];   // 32KB
    const int rb = blockIdx.x;
    const int t = threadIdx.x;
    const int lane = t & 63, wave = t >> 6;
    const int wm = wave >> 1, wn = wave & 1;
    const int l15 = lane & 15, l4 = lane >> 4;

    f32x4 acc[4];
    #pragma unroll
    for (int j = 0; j < 4; ++j) acc[j] = (f32x4){0.f, 0.f, 0.f, 0.f};

    for (int kc = 0; kc < 4; ++kc) {
        #pragma unroll
        for (int q = 0; q < 2; ++q) {       // A: 8KB
            const int o = t * 16 + q * 4096;
            const int arow = o >> 8, ob = o & 255;
            g2l16((const char*)Obf + (size_t)(rb * 32 + arow) * 1024 + kc * 256 + ob,
                  (char*)As + o);
        }
        #pragma unroll
        for (int q = 0; q < 8; ++q) {       // B: 32KB
            const int o = t * 16 + q * 4096;
            const int c = o >> 8, ob = o & 255;
            g2l16((const char*)OWbf + (size_t)c * 1024 + kc * 256 + ob,
                  (char*)Bs + o);
        }
        __syncthreads();
        #pragma unroll
        for (int ks = 0; ks < 4; ++ks) {
            const int kb = ks * 64 + l4 * 16;
            bf16x8 a0, bb[4];
            {
                const int row = wm * 16 + l15;
                a0 = *(const bf16x8*)((const char*)As + row * 256 + (kb ^ ((row & 7) << 4)));
            }
            #pragma unroll
            for (int fn = 0; fn < 4; ++fn) {
                const int col = wn * 64 + fn * 16 + l15;
                bb[fn] = *(const bf16x8*)((const char*)Bs + col * 256 + (kb ^ ((col & 7) << 4)));
            }
            #pragma unroll
            for (int fn = 0; fn < 4; ++fn)
                acc[fn] = __builtin_amdgcn_mfma_f32_16x16x32_bf16(
                    a0, bb[fn], acc[fn], 0, 0, 0);
        }
        __syncthreads();
    }

    #pragma unroll
    for (int fn = 0; fn < 4; ++fn) {
        const int col = wn * 64 + fn * 16 + l15;
        const float bv = bo[col];
        #pragma unroll
        for (int r = 0; r < 4; ++r) {
            const int row = rb * 32 + wm * 16 + l4 * 4 + r;
            Out[(size_t)row * OUT_ + col] = acc[fn][r] + bv;
        }
    }
}

// ---------------------------------------------------------------------------
extern "C" void kernel_launch(void* const* d_in, const int* in_sizes, int n_in,
                              void* d_out, int out_size, void* d_ws, size_t ws_size,
                              hipStream_t stream)
{
    const float* x     = (const float*)d_in[0];
    const int*   nidx  = (const int*)  d_in[1];
    const float* attr  = (const float*)d_in[2];
    const float* wq_w  = (const float*)d_in[3];
    const float* wq_b  = (const float*)d_in[4];
    const float* wk_w  = (const float*)d_in[5];
    const float* wk_b  = (const float*)d_in[6];
    const float* wv_w  = (const float*)d_in[7];
    const float* wv_b  = (const float*)d_in[8];
    const float* out_w = (const float*)d_in[9];
    const float* out_b = (const float*)d_in[10];
    float* out = (float*)d_out;

    char* ws = (char*)d_ws;
    size_t off = 0;
    auto alloc = [&](size_t bytes) -> char* {
        char* p = ws + off;
        off += (bytes + 255) & ~(size_t)255;
        return p;
    };
    u16*  QKV  = (u16*)alloc((size_t)M_ * C3_ * 2);         // 24MB
    u16*  OWbf = (u16*)alloc((size_t)OUT_ * HD_ * 2);       // 128KB
    u16*  Obf  = (u16*)alloc((size_t)M_ * HD_ * 2);         // 8MB
    float* vsum = (float*)alloc((size_t)B_ * H_ * D_ * 4);  // 8KB
    int*  row_count = (int*)alloc((size_t)B_ * N_ * 4);     // 32KB
    int2* row_edges = (int2*)alloc((size_t)B_ * N_ * CAP * 8);

    hipMemsetAsync(row_count, 0, (size_t)B_ * N_ * 4, stream);
    hipMemsetAsync(vsum, 0, (size_t)B_ * H_ * D_ * 4, stream);

    qkv_append<<<768 + 4096 + 32, 256, 0, stream>>>(
        x, wq_w, wk_w, wv_w, wq_b, wk_b, wv_b, out_w, nidx, attr,
        QKV, vsum, row_count, row_edges, OWbf);
    row_fused<<<2048, 256, 0, stream>>>(
        QKV, vsum, row_count, row_edges, Obf);
    out_mfma<<<M_ / 32, 256, 0, stream>>>(Obf, OWbf, out_b, out);
}

// Round 10
// 81.054 us; speedup vs baseline: 1.1159x; 1.1159x over previous
//
#include <hip/hip_runtime.h>
#include <hip/hip_bf16.h>
#include <math.h>

// Problem constants
constexpr int B_ = 4;
constexpr int N_ = 2048;
constexpr int D_ = 128;
constexpr int H_ = 4;
constexpr int E_ = 32768;
constexpr int W_ = 8;
constexpr int OUT_ = 128;
constexpr int HD_ = H_ * D_;    // 512
constexpr int C3_ = 3 * HD_;    // 1536 combined QKV cols
constexpr int CAP = 64;         // max edges per row bucket (Poisson(16))
constexpr int M_ = B_ * N_;     // 8192 rows

typedef __attribute__((ext_vector_type(8))) __bf16 bf16x8;
typedef __attribute__((ext_vector_type(4))) float f32x4;
typedef unsigned int uint32;
typedef unsigned short u16;

__device__ __forceinline__ u16 f2b(float f) {
    __hip_bfloat16 h = __float2bfloat16(f);
    return *(u16*)&h;
}
__device__ __forceinline__ float blo(uint32 u) { return __uint_as_float(u << 16); }
__device__ __forceinline__ float bhi(uint32 u) { return __uint_as_float(u & 0xffff0000u); }

// async 16B global->LDS copy (dest = wave-uniform base + lane*16)
__device__ __forceinline__ void g2l16(const void* g, void* l) {
    __builtin_amdgcn_global_load_lds(
        (const __attribute__((address_space(1))) unsigned int*)(uintptr_t)g,
        (__attribute__((address_space(3))) unsigned int*)(uintptr_t)l,
        16, 0, 0);
}

// ---------------------------------------------------------------------------
// K1 prep_append: NO LDS anywhere -> latency-bound blocks run at full
// occupancy.  Block ranges:
// [0,512):      cast x -> Xbf (plain row-major [8192][128] bf16)
// [512,608):    cast 12 weight mats -> Wbf (plain [12][128][128]) + biasf
// [608,640):    cast out_w -> OWbf (swizzled for out_mfma's g2l16 path)
// [640,4736):   edge append, 8 edges/wave, fully parallel
// row_count/vsum zeroed by a preceding hipMemsetAsync.
// ---------------------------------------------------------------------------
__global__ __launch_bounds__(256) void prep_append(
    const float* __restrict__ X,
    const float* __restrict__ wq, const float* __restrict__ wk, const float* __restrict__ wv,
    const float* __restrict__ bq, const float* __restrict__ bk, const float* __restrict__ bv,
    const float* __restrict__ OW,
    const int* __restrict__ nidx, const float* __restrict__ attr,
    u16* __restrict__ Xbf, u16* __restrict__ Wbf, float* __restrict__ biasf,
    u16* __restrict__ OWbf,
    int* __restrict__ row_count, int2* __restrict__ row_edges)
{
    const int blk = blockIdx.x;
    const int t = threadIdx.x;
    if (blk < 512) {                       // ---- cast_x (plain) ----
        const int tid = blk * 256 + t;     // 16B chunk id
        const float4 f0 = *(const float4*)(X + (size_t)tid * 8);
        const float4 f1 = *(const float4*)(X + (size_t)tid * 8 + 4);
        union { u16 u[8]; uint4 v; } pk;
        pk.u[0]=f2b(f0.x); pk.u[1]=f2b(f0.y); pk.u[2]=f2b(f0.z); pk.u[3]=f2b(f0.w);
        pk.u[4]=f2b(f1.x); pk.u[5]=f2b(f1.y); pk.u[6]=f2b(f1.z); pk.u[7]=f2b(f1.w);
        *(uint4*)((char*)Xbf + (size_t)tid * 16) = pk.v;
    } else if (blk < 608) {                // ---- cast_w (plain) + bias ----
        const int c = (blk - 512) * 256 + t;   // 0..24575 chunks
        const int g = c >> 11, idx = c & 2047;
        const int t3 = g >> 2, h = g & 3;
        const float* Wsrc = (t3 == 0 ? wq : t3 == 1 ? wk : wv) + (size_t)h * 128 * 128;
        const float4 f0 = *(const float4*)(Wsrc + (size_t)idx * 8);
        const float4 f1 = *(const float4*)(Wsrc + (size_t)idx * 8 + 4);
        union { u16 u[8]; uint4 v; } pk;
        pk.u[0]=f2b(f0.x); pk.u[1]=f2b(f0.y); pk.u[2]=f2b(f0.z); pk.u[3]=f2b(f0.w);
        pk.u[4]=f2b(f1.x); pk.u[5]=f2b(f1.y); pk.u[6]=f2b(f1.z); pk.u[7]=f2b(f1.w);
        *(uint4*)((char*)Wbf + (size_t)c * 16) = pk.v;
        if (idx < 128) {
            const float* Bsrc = (t3 == 0 ? bq : t3 == 1 ? bk : bv) + h * 128;
            biasf[g * 128 + idx] = Bsrc[idx];
        }
    } else if (blk < 640) {                // ---- cast_ow (swizzled) ----
        const int tid = (blk - 608) * 256 + t;  // 0..8191
        const int c = tid >> 6, sub = tid & 63;
        const float4 f0 = *(const float4*)(OW + (size_t)c * 512 + sub * 8);
        const float4 f1 = *(const float4*)(OW + (size_t)c * 512 + sub * 8 + 4);
        union { u16 u[8]; uint4 v; } pk;
        pk.u[0]=f2b(f0.x); pk.u[1]=f2b(f0.y); pk.u[2]=f2b(f0.z); pk.u[3]=f2b(f0.w);
        pk.u[4]=f2b(f1.x); pk.u[5]=f2b(f1.y); pk.u[6]=f2b(f1.z); pk.u[7]=f2b(f1.w);
        const int ob = c * 1024 + ((sub * 16) ^ ((c & 7) << 4));
        *(uint4*)((char*)OWbf + ob) = pk.v;
    } else {                               // ---- append ----
        const int wave = t >> 6, lane = t & 63;
        const int gw = (blk - 640) * 4 + wave;    // 0..16383
        const int e0g = gw * 8;
        const int b = e0g / E_;
        const int e0 = e0g % E_;
        float a = attr[((size_t)b * E_ + e0) * W_ + lane];
        a += __shfl_xor(a, 1);
        a += __shfl_xor(a, 2);
        a += __shfl_xor(a, 4);
        if ((lane & 7) == 0) {
            const int sub = lane >> 3;
            const int e = e0 + sub;
            const int i = nidx[b * 2 * E_ + e];
            const int j = nidx[b * 2 * E_ + E_ + e];
            const int pos = atomicAdd(&row_count[b * N_ + i], 1);
            if (pos < CAP)
                row_edges[(size_t)(b * N_ + i) * CAP + pos] =
                    make_int2(e | (j << 16), __float_as_int(a));
        }
    }
}

// ---------------------------------------------------------------------------
// K2 qkv_gemm: QKV[8192][1536] bf16 = Xbf x Wbf^T + bias.  768 blocks, all
// co-resident (3/CU).  A/B fragments loaded bf16-direct from global
// (L2-resident); 32KB LDS only for the C repack; V col-blocks reduce vsum.
// ---------------------------------------------------------------------------
__global__ __launch_bounds__(256) void qkv_gemm(
    const u16* __restrict__ Xbf, const u16* __restrict__ Wbf,
    const float* __restrict__ biasf, u16* __restrict__ QKV,
    float* __restrict__ vsum)
{
    __shared__ u16 Cs[128 * 128];          // 32KB (repack only)
    const int t = threadIdx.x;
    const int lane = t & 63, wave = t >> 6;
    const int rb = blockIdx.x & 63;
    const int g  = blockIdx.x >> 6;
    const int wm = wave >> 1, wn = wave & 1;
    const int l15 = lane & 15, l4 = lane >> 4;

    const u16* Abase = Xbf + (size_t)(rb * 128) * 128;
    const u16* Bbase = Wbf + (size_t)(g  * 128) * 128;

    f32x4 acc[4][4];
    #pragma unroll
    for (int i = 0; i < 4; ++i)
        #pragma unroll
        for (int j = 0; j < 4; ++j) acc[i][j] = (f32x4){0.f, 0.f, 0.f, 0.f};

    #pragma unroll
    for (int ks = 0; ks < 4; ++ks) {
        const int ko = ks * 32 + l4 * 8;
        bf16x8 a[4], bb[4];
        #pragma unroll
        for (int fm = 0; fm < 4; ++fm)
            a[fm] = *(const bf16x8*)(Abase + (wm * 64 + fm * 16 + l15) * 128 + ko);
        #pragma unroll
        for (int fn = 0; fn < 4; ++fn)
            bb[fn] = *(const bf16x8*)(Bbase + (wn * 64 + fn * 16 + l15) * 128 + ko);
        #pragma unroll
        for (int fm = 0; fm < 4; ++fm)
            #pragma unroll
            for (int fn = 0; fn < 4; ++fn)
                acc[fm][fn] = __builtin_amdgcn_mfma_f32_16x16x32_bf16(
                    a[fm], bb[fn], acc[fm][fn], 0, 0, 0);
    }

    // write acc (+bias) into Cs as swizzled bf16 [row][256B]
    #pragma unroll
    for (int fm = 0; fm < 4; ++fm)
        #pragma unroll
        for (int fn = 0; fn < 4; ++fn) {
            const int col = wn * 64 + fn * 16 + l15;
            const float bv = biasf[g * 128 + col];
            #pragma unroll
            for (int r = 0; r < 4; ++r) {
                const int row = wm * 64 + fm * 16 + l4 * 4 + r;
                *(u16*)((char*)Cs + row * 256 + ((col * 2) ^ ((row & 7) << 4))) =
                    f2b(acc[fm][fn][r] + bv);
            }
        }

    if (g >= 8) {   // fused V column-sum (includes bias via +64*bv per wave)
        const int h = g - 8;
        const int b = rb >> 4;      // 16 row-blocks per batch
        #pragma unroll
        for (int fn = 0; fn < 4; ++fn) {
            float s = 0.f;
            #pragma unroll
            for (int fm = 0; fm < 4; ++fm)
                #pragma unroll
                for (int r = 0; r < 4; ++r) s += acc[fm][fn][r];
            s += __shfl_xor(s, 16);
            s += __shfl_xor(s, 32);
            if (l4 == 0) {
                const int col = wn * 64 + fn * 16 + l15;
                const float bv = biasf[g * 128 + col];
                atomicAdd(&vsum[(b * H_ + h) * 128 + col], s + 64.f * bv);
            }
        }
    }
    __syncthreads();

    // coalesced store: 8 x uint4 per thread
    #pragma unroll
    for (int q = 0; q < 8; ++q) {
        const int idx = t + q * 256;          // chunk 0..2047
        const int row = idx >> 4, c = idx & 15;
        const uint4 v = *(const uint4*)((char*)Cs + row * 256 + ((c * 16) ^ ((row & 7) << 4)));
        *(uint4*)(QKV + (size_t)(rb * 128 + row) * C3_ + g * 128 + c * 8) = v;
    }
}

// ---------------------------------------------------------------------------
// row_fused: wave-per-row scoring + sparse softmax + PV (dual accumulator
// chains + pair prefetch), XCD-pinned batch mapping: xcd = blockIdx.x & 7
// (round-robin dispatch); batch = xcd>>1 so each XCD's 4MB L2 holds exactly
// one batch's K+V slab.
// ---------------------------------------------------------------------------
__global__ __launch_bounds__(256) void row_fused(
    const u16* __restrict__ QKV, const float* __restrict__ vsum,
    const int* __restrict__ row_count, const int2* __restrict__ row_edges,
    u16* __restrict__ Obf)
{
    const int t = threadIdx.x;
    const int wave = t >> 6, lane = t & 63;
    const int gid = blockIdx.x;                 // 0..2047
    const int xcd = gid & 7;
    const int b = xcd >> 1;                     // 2 XCDs per batch
    const int rowgrp = ((xcd & 1) << 8) | (gid >> 3);   // 0..511
    const int row = rowgrp * 4 + wave;
    const int R = b * N_ + row;
    int cnt = row_count[R];
    if (cnt > CAP) cnt = CAP;

    // edge entries register-resident: lane p < cnt holds entry p
    int ej = 0; float ws = 0.f;
    if (lane < cnt) {
        const int2 v = row_edges[(size_t)R * CAP + lane];
        ej = v.x; ws = __int_as_float(v.y);
    }
    // last-e-wins dedup via shfl broadcast (winner = max e per j)
    const int myj = ej >> 16, mye = ej & 0xFFFF;
    bool win = (lane < cnt);
    for (int p = 0; p < cnt; ++p) {
        const int oj = __shfl(ej, p);
        if (win && (oj >> 16) == myj && (oj & 0xFFFF) > mye) win = false;
    }
    unsigned long long m = __ballot(win);

    const char* base = (const char*)QKV;
    const uint4 qv = *(const uint4*)(base + (size_t)R * 3072 + lane * 16);
    const float q0=blo(qv.x), q1=bhi(qv.x), q2=blo(qv.y), q3=bhi(qv.y),
                q4=blo(qv.z), q5=bhi(qv.z), q6=blo(qv.w), q7=bhi(qv.w);
    const float rs = 0.02209708691207961f;   // 1/sqrt(2048)

    float A0=0.f,A1=0.f,A2=0.f,A3=0.f,A4=0.f,A5=0.f,A6=0.f,A7=0.f;
    float B0=0.f,B1=0.f,B2=0.f,B3=0.f,B4=0.f,B5=0.f,B6=0.f,B7=0.f;
    float dsA = 0.f, dsB = 0.f;

#define FETCH(MM, KV1,VV1,W1,KV2,VV2,W2,NN)                                  \
    { int p_ = (int)__ffsll((long long)MM) - 1; MM &= MM - 1;                \
      const int j_ = __shfl(ej, p_) >> 16; W1 = __shfl(ws, p_);              \
      const char* nb_ = base + (size_t)(b * N_ + j_) * 3072;                 \
      KV1 = *(const uint4*)(nb_ + 1024 + lane * 16);                         \
      VV1 = *(const uint4*)(nb_ + 2048 + lane * 16);                         \
      if (MM) {                                                              \
        int q_ = (int)__ffsll((long long)MM) - 1; MM &= MM - 1;              \
        const int j2_ = __shfl(ej, q_) >> 16; W2 = __shfl(ws, q_);           \
        const char* nb2_ = base + (size_t)(b * N_ + j2_) * 3072;             \
        KV2 = *(const uint4*)(nb2_ + 1024 + lane * 16);                      \
        VV2 = *(const uint4*)(nb2_ + 2048 + lane * 16);                      \
        NN = 2;                                                              \
      } else NN = 1; }

#define PROC(kv, vv, wsp, S)                                                 \
    { float s_ = q0*blo(kv.x) + q1*bhi(kv.x) + q2*blo(kv.y) + q3*bhi(kv.y)   \
               + q4*blo(kv.z) + q5*bhi(kv.z) + q6*blo(kv.w) + q7*bhi(kv.w);  \
      s_ += __shfl_xor(s_, 1);                                               \
      s_ += __shfl_xor(s_, 2);                                               \
      s_ += __shfl_xor(s_, 4);                                               \
      s_ += __shfl_xor(s_, 8);                                               \
      const float x_ = expf(s_ * rs * (wsp)) - 1.f;                          \
      ds##S += x_;                                                           \
      S##0 = fmaf(x_, blo(vv.x), S##0); S##1 = fmaf(x_, bhi(vv.x), S##1);    \
      S##2 = fmaf(x_, blo(vv.y), S##2); S##3 = fmaf(x_, bhi(vv.y), S##3);    \
      S##4 = fmaf(x_, blo(vv.z), S##4); S##5 = fmaf(x_, bhi(vv.z), S##5);    \
      S##6 = fmaf(x_, blo(vv.w), S##6); S##7 = fmaf(x_, bhi(vv.w), S##7); }

    if (m) {
        uint4 kv1, vv1, kv2, vv2; float w1, w2; int n1;
        FETCH(m, kv1, vv1, w1, kv2, vv2, w2, n1);
        while (m) {
            uint4 nk1, nv1, nk2, nv2; float nw1, nw2; int n2;
            FETCH(m, nk1, nv1, nw1, nk2, nv2, nw2, n2);
            PROC(kv1, vv1, w1, A);
            if (n1 == 2) PROC(kv2, vv2, w2, B);
            kv1 = nk1; vv1 = nv1; w1 = nw1;
            kv2 = nk2; vv2 = nv2; w2 = nw2; n1 = n2;
        }
        PROC(kv1, vv1, w1, A);
        if (n1 == 2) PROC(kv2, vv2, w2, B);
    }
#undef FETCH
#undef PROC

    const float inv = 1.0f / (2048.0f + dsA + dsB);
    const float* vsp = vsum + (b * H_ + (lane >> 4)) * 128 + (lane & 15) * 8;
    const float4 vs0 = *(const float4*)vsp;
    const float4 vs1 = *(const float4*)(vsp + 4);
    union { u16 u[8]; uint4 v; } o;
    o.u[0]=f2b((vs0.x+A0+B0)*inv); o.u[1]=f2b((vs0.y+A1+B1)*inv);
    o.u[2]=f2b((vs0.z+A2+B2)*inv); o.u[3]=f2b((vs0.w+A3+B3)*inv);
    o.u[4]=f2b((vs1.x+A4+B4)*inv); o.u[5]=f2b((vs1.y+A5+B5)*inv);
    o.u[6]=f2b((vs1.z+A6+B6)*inv); o.u[7]=f2b((vs1.w+A7+B7)*inv);
    const int ob = ((lane >> 4) << 8) + (((lane & 15) * 16) ^ ((R & 7) << 4));
    *(uint4*)((char*)Obf + (size_t)R * 1024 + ob) = o.v;
}

// ---------------------------------------------------------------------------
// out_mfma: d_out[8192][128] f32 = Obf[8192][512] x OWbf[128][512]^T + out_b
// grid = 256 row-blocks (M-tile 32), 4 waves (2x2), wave tile 16x64.
// ---------------------------------------------------------------------------
__global__ __launch_bounds__(256) void out_mfma(
    const u16* __restrict__ Obf, const u16* __restrict__ OWbf,
    const float* __restrict__ bo, float* __restrict__ Out)
{
    __shared__ u16 As[32 * 128];    // 8KB
    __shared__ u16 Bs[128 * 128];   // 32KB
    const int rb = blockIdx.x;
    const int t = threadIdx.x;
    const int lane = t & 63, wave = t >> 6;
    const int wm = wave >> 1, wn = wave & 1;
    const int l15 = lane & 15, l4 = lane >> 4;

    f32x4 acc[4];
    #pragma unroll
    for (int j = 0; j < 4; ++j) acc[j] = (f32x4){0.f, 0.f, 0.f, 0.f};

    for (int kc = 0; kc < 4; ++kc) {
        #pragma unroll
        for (int q = 0; q < 2; ++q) {       // A: 8KB
            const int o = t * 16 + q * 4096;
            const int arow = o >> 8, ob = o & 255;
            g2l16((const char*)Obf + (size_t)(rb * 32 + arow) * 1024 + kc * 256 + ob,
                  (char*)As + o);
        }
        #pragma unroll
        for (int q = 0; q < 8; ++q) {       // B: 32KB
            const int o = t * 16 + q * 4096;
            const int c = o >> 8, ob = o & 255;
            g2l16((const char*)OWbf + (size_t)c * 1024 + kc * 256 + ob,
                  (char*)Bs + o);
        }
        __syncthreads();
        #pragma unroll
        for (int ks = 0; ks < 4; ++ks) {
            const int kb = ks * 64 + l4 * 16;
            bf16x8 a0, bb[4];
            {
                const int row = wm * 16 + l15;
                a0 = *(const bf16x8*)((const char*)As + row * 256 + (kb ^ ((row & 7) << 4)));
            }
            #pragma unroll
            for (int fn = 0; fn < 4; ++fn) {
                const int col = wn * 64 + fn * 16 + l15;
                bb[fn] = *(const bf16x8*)((const char*)Bs + col * 256 + (kb ^ ((col & 7) << 4)));
            }
            #pragma unroll
            for (int fn = 0; fn < 4; ++fn)
                acc[fn] = __builtin_amdgcn_mfma_f32_16x16x32_bf16(
                    a0, bb[fn], acc[fn], 0, 0, 0);
        }
        __syncthreads();
    }

    #pragma unroll
    for (int fn = 0; fn < 4; ++fn) {
        const int col = wn * 64 + fn * 16 + l15;
        const float bv = bo[col];
        #pragma unroll
        for (int r = 0; r < 4; ++r) {
            const int row = rb * 32 + wm * 16 + l4 * 4 + r;
            Out[(size_t)row * OUT_ + col] = acc[fn][r] + bv;
        }
    }
}

// ---------------------------------------------------------------------------
extern "C" void kernel_launch(void* const* d_in, const int* in_sizes, int n_in,
                              void* d_out, int out_size, void* d_ws, size_t ws_size,
                              hipStream_t stream)
{
    const float* x     = (const float*)d_in[0];
    const int*   nidx  = (const int*)  d_in[1];
    const float* attr  = (const float*)d_in[2];
    const float* wq_w  = (const float*)d_in[3];
    const float* wq_b  = (const float*)d_in[4];
    const float* wk_w  = (const float*)d_in[5];
    const float* wk_b  = (const float*)d_in[6];
    const float* wv_w  = (const float*)d_in[7];
    const float* wv_b  = (const float*)d_in[8];
    const float* out_w = (const float*)d_in[9];
    const float* out_b = (const float*)d_in[10];
    float* out = (float*)d_out;

    char* ws = (char*)d_ws;
    size_t off = 0;
    auto alloc = [&](size_t bytes) -> char* {
        char* p = ws + off;
        off += (bytes + 255) & ~(size_t)255;
        return p;
    };
    u16*  QKV  = (u16*)alloc((size_t)M_ * C3_ * 2);         // 24MB
    u16*  Xbf  = (u16*)alloc((size_t)M_ * D_ * 2);          // 2MB
    u16*  Wbf  = (u16*)alloc((size_t)12 * D_ * D_ * 2);     // 384KB
    float* biasf = (float*)alloc((size_t)12 * D_ * 4);      // 6KB
    u16*  OWbf = (u16*)alloc((size_t)OUT_ * HD_ * 2);       // 128KB
    u16*  Obf  = (u16*)alloc((size_t)M_ * HD_ * 2);         // 8MB
    float* vsum = (float*)alloc((size_t)B_ * H_ * D_ * 4);  // 8KB
    int*  row_count = (int*)alloc((size_t)B_ * N_ * 4);     // 32KB (contiguous after vsum)
    int2* row_edges = (int2*)alloc((size_t)B_ * N_ * CAP * 8);

    // vsum + row_count are contiguous: one 40KB zero-fill
    hipMemsetAsync(vsum, 0, (size_t)B_ * H_ * D_ * 4 + (size_t)B_ * N_ * 4, stream);

    prep_append<<<640 + 4096, 256, 0, stream>>>(
        x, wq_w, wk_w, wv_w, wq_b, wk_b, wv_b, out_w, nidx, attr,
        Xbf, Wbf, biasf, OWbf, row_count, row_edges);
    qkv_gemm<<<768, 256, 0, stream>>>(Xbf, Wbf, biasf, QKV, vsum);
    row_fused<<<2048, 256, 0, stream>>>(
        QKV, vsum, row_count, row_edges, Obf);
    out_mfma<<<M_ / 32, 256, 0, stream>>>(Obf, OWbf, out_b, out);
}

// Round 11
// 75.923 us; speedup vs baseline: 1.1913x; 1.0676x over previous
//
#include <hip/hip_runtime.h>
#include <hip/hip_bf16.h>
#include <math.h>

// Problem constants
constexpr int B_ = 4;
constexpr int N_ = 2048;
constexpr int D_ = 128;
constexpr int H_ = 4;
constexpr int E_ = 32768;
constexpr int W_ = 8;
constexpr int OUT_ = 128;
constexpr int HD_ = H_ * D_;    // 512
constexpr int C3_ = 3 * HD_;    // 1536 combined QKV cols
constexpr int CAP = 64;         // max edges per row bucket (Poisson(16))
constexpr int M_ = B_ * N_;     // 8192 rows

typedef __attribute__((ext_vector_type(8))) __bf16 bf16x8;
typedef __attribute__((ext_vector_type(4))) float f32x4;
typedef unsigned int uint32;
typedef unsigned short u16;

__device__ __forceinline__ u16 f2b(float f) {
    __hip_bfloat16 h = __float2bfloat16(f);
    return *(u16*)&h;
}
__device__ __forceinline__ float blo(uint32 u) { return __uint_as_float(u << 16); }
__device__ __forceinline__ float bhi(uint32 u) { return __uint_as_float(u & 0xffff0000u); }

// async 16B global->LDS copy (dest = wave-uniform base + lane*16)
__device__ __forceinline__ void g2l16(const void* g, void* l) {
    __builtin_amdgcn_global_load_lds(
        (const __attribute__((address_space(1))) unsigned int*)(uintptr_t)g,
        (__attribute__((address_space(3))) unsigned int*)(uintptr_t)l,
        16, 0, 0);
}

// ---------------------------------------------------------------------------
// prep_kernel: fused casts + zero(row_count, vsum).
// blocks [0,512): cast x -> Xbf (PLAIN row-major [8192][128])
// blocks [512,608): cast 12 weight mats -> Wbf (PLAIN [12][128][128]) + bias
// blocks [608,640): cast out_w -> OWbf (swizzled, for out_mfma g2l16 path)
// block 640: zero row_count (32KB) + vsum (8KB)
// ---------------------------------------------------------------------------
__global__ __launch_bounds__(256) void prep_kernel(
    const float* __restrict__ X,
    const float* __restrict__ wq, const float* __restrict__ wk, const float* __restrict__ wv,
    const float* __restrict__ bq, const float* __restrict__ bk, const float* __restrict__ bv,
    const float* __restrict__ OW,
    u16* __restrict__ Xbf, u16* __restrict__ Wbf, float* __restrict__ biasf,
    u16* __restrict__ OWbf,
    int* __restrict__ row_count, float* __restrict__ vsum)
{
    const int blk = blockIdx.x;
    if (blk < 512) {                       // ---- cast_x (plain) ----
        const int tid = blk * 256 + threadIdx.x;     // 16B chunk id
        const float4 f0 = *(const float4*)(X + (size_t)tid * 8);
        const float4 f1 = *(const float4*)(X + (size_t)tid * 8 + 4);
        union { u16 u[8]; uint4 v; } pk;
        pk.u[0]=f2b(f0.x); pk.u[1]=f2b(f0.y); pk.u[2]=f2b(f0.z); pk.u[3]=f2b(f0.w);
        pk.u[4]=f2b(f1.x); pk.u[5]=f2b(f1.y); pk.u[6]=f2b(f1.z); pk.u[7]=f2b(f1.w);
        *(uint4*)((char*)Xbf + (size_t)tid * 16) = pk.v;
    } else if (blk < 608) {                // ---- cast_w (plain) + bias ----
        const int c = (blk - 512) * 256 + threadIdx.x;   // 0..24575 chunks
        const int g = c >> 11, idx = c & 2047;
        const int t3 = g >> 2, h = g & 3;
        const float* Wsrc = (t3 == 0 ? wq : t3 == 1 ? wk : wv) + (size_t)h * 128 * 128;
        const float4 f0 = *(const float4*)(Wsrc + (size_t)idx * 8);
        const float4 f1 = *(const float4*)(Wsrc + (size_t)idx * 8 + 4);
        union { u16 u[8]; uint4 v; } pk;
        pk.u[0]=f2b(f0.x); pk.u[1]=f2b(f0.y); pk.u[2]=f2b(f0.z); pk.u[3]=f2b(f0.w);
        pk.u[4]=f2b(f1.x); pk.u[5]=f2b(f1.y); pk.u[6]=f2b(f1.z); pk.u[7]=f2b(f1.w);
        *(uint4*)((char*)Wbf + (size_t)c * 16) = pk.v;
        if (idx < 128) {
            const float* Bsrc = (t3 == 0 ? bq : t3 == 1 ? bk : bv) + h * 128;
            biasf[g * 128 + idx] = Bsrc[idx];
        }
    } else if (blk < 640) {                // ---- cast_ow (swizzled) ----
        const int tid = (blk - 608) * 256 + threadIdx.x;  // 0..8191
        const int c = tid >> 6, sub = tid & 63;
        const float4 f0 = *(const float4*)(OW + (size_t)c * 512 + sub * 8);
        const float4 f1 = *(const float4*)(OW + (size_t)c * 512 + sub * 8 + 4);
        union { u16 u[8]; uint4 v; } pk;
        pk.u[0]=f2b(f0.x); pk.u[1]=f2b(f0.y); pk.u[2]=f2b(f0.z); pk.u[3]=f2b(f0.w);
        pk.u[4]=f2b(f1.x); pk.u[5]=f2b(f1.y); pk.u[6]=f2b(f1.z); pk.u[7]=f2b(f1.w);
        const int ob = c * 1024 + ((sub * 16) ^ ((c & 7) << 4));
        *(uint4*)((char*)OWbf + ob) = pk.v;
    } else {                               // ---- zero row_count + vsum ----
        const uint4 z = make_uint4(0, 0, 0, 0);
        uint4* rc = (uint4*)row_count;     // 2048 uint4 = 32KB
        #pragma unroll
        for (int q = 0; q < 8; ++q) rc[threadIdx.x + q * 256] = z;
        uint4* vs = (uint4*)vsum;          // 512 uint4 = 8KB
        #pragma unroll
        for (int q = 0; q < 2; ++q) vs[threadIdx.x + q * 256] = z;
    }
}

// ---------------------------------------------------------------------------
// qkv_append: QKV GEMM without staging LDS (blocks [0,768)) + edge append
// (blocks [768,4864), one 8-edge pass per wave — fully parallel).
// GEMM: MFMA A/B fragments loaded directly from global (L2-resident);
// 32KB LDS used only for the C repack -> coalesced uint4 stores.
// ---------------------------------------------------------------------------
__global__ __launch_bounds__(256) void qkv_append(
    const u16* __restrict__ Xbf, const u16* __restrict__ Wbf,
    const float* __restrict__ biasf,
    const int* __restrict__ nidx, const float* __restrict__ attr,
    u16* __restrict__ QKV, float* __restrict__ vsum,
    int* __restrict__ row_count, int2* __restrict__ row_edges)
{
    __shared__ u16 Cs[128 * 128];          // 32KB (repack only)
    const int t = threadIdx.x;
    const int lane = t & 63, wave = t >> 6;

    if (blockIdx.x >= 768) {               // ---- append path (no LDS use) ----
        const int gw = (blockIdx.x - 768) * 4 + wave;    // 0..16383
        const int e0g = gw * 8;
        const int b = e0g / E_;
        const int e0 = e0g % E_;
        float a = attr[((size_t)b * E_ + e0) * W_ + lane];
        a += __shfl_xor(a, 1);
        a += __shfl_xor(a, 2);
        a += __shfl_xor(a, 4);
        if ((lane & 7) == 0) {
            const int sub = lane >> 3;
            const int e = e0 + sub;
            const int i = nidx[b * 2 * E_ + e];
            const int j = nidx[b * 2 * E_ + E_ + e];
            const int pos = atomicAdd(&row_count[b * N_ + i], 1);
            if (pos < CAP)
                row_edges[(size_t)(b * N_ + i) * CAP + pos] =
                    make_int2(e | (j << 16), __float_as_int(a));
        }
        return;
    }

    // ---- gemm path ----
    const int rb = blockIdx.x & 63;
    const int g  = blockIdx.x >> 6;
    const int wm = wave >> 1, wn = wave & 1;
    const int l15 = lane & 15, l4 = lane >> 4;

    const u16* Abase = Xbf + (size_t)(rb * 128) * 128;
    const u16* Bbase = Wbf + (size_t)(g  * 128) * 128;

    f32x4 acc[4][4];
    #pragma unroll
    for (int i = 0; i < 4; ++i)
        #pragma unroll
        for (int j = 0; j < 4; ++j) acc[i][j] = (f32x4){0.f, 0.f, 0.f, 0.f};

    #pragma unroll
    for (int ks = 0; ks < 4; ++ks) {
        const int ko = ks * 32 + l4 * 8;
        bf16x8 a[4], bb[4];
        #pragma unroll
        for (int fm = 0; fm < 4; ++fm)
            a[fm] = *(const bf16x8*)(Abase + (wm * 64 + fm * 16 + l15) * 128 + ko);
        #pragma unroll
        for (int fn = 0; fn < 4; ++fn)
            bb[fn] = *(const bf16x8*)(Bbase + (wn * 64 + fn * 16 + l15) * 128 + ko);
        #pragma unroll
        for (int fm = 0; fm < 4; ++fm)
            #pragma unroll
            for (int fn = 0; fn < 4; ++fn)
                acc[fm][fn] = __builtin_amdgcn_mfma_f32_16x16x32_bf16(
                    a[fm], bb[fn], acc[fm][fn], 0, 0, 0);
    }

    // write acc (+bias) into Cs as swizzled bf16 [row][256B]
    #pragma unroll
    for (int fm = 0; fm < 4; ++fm)
        #pragma unroll
        for (int fn = 0; fn < 4; ++fn) {
            const int col = wn * 64 + fn * 16 + l15;
            const float bv = biasf[g * 128 + col];
            #pragma unroll
            for (int r = 0; r < 4; ++r) {
                const int row = wm * 64 + fm * 16 + l4 * 4 + r;
                *(u16*)((char*)Cs + row * 256 + ((col * 2) ^ ((row & 7) << 4))) =
                    f2b(acc[fm][fn][r] + bv);
            }
        }

    if (g >= 8) {   // fused V column-sum (includes bias via +64*bv per wave)
        const int h = g - 8;
        const int b = rb >> 4;      // 16 row-blocks per batch
        #pragma unroll
        for (int fn = 0; fn < 4; ++fn) {
            float s = 0.f;
            #pragma unroll
            for (int fm = 0; fm < 4; ++fm)
                #pragma unroll
                for (int r = 0; r < 4; ++r) s += acc[fm][fn][r];
            s += __shfl_xor(s, 16);
            s += __shfl_xor(s, 32);
            if (l4 == 0) {
                const int col = wn * 64 + fn * 16 + l15;
                const float bv = biasf[g * 128 + col];
                atomicAdd(&vsum[(b * H_ + h) * 128 + col], s + 64.f * bv);
            }
        }
    }
    __syncthreads();

    // coalesced store: 8 x uint4 per thread
    #pragma unroll
    for (int q = 0; q < 8; ++q) {
        const int idx = t + q * 256;          // chunk 0..2047
        const int row = idx >> 4, c = idx & 15;
        const uint4 v = *(const uint4*)((char*)Cs + row * 256 + ((c * 16) ^ ((row & 7) << 4)));
        *(uint4*)(QKV + (size_t)(rb * 128 + row) * C3_ + g * 128 + c * 8) = v;
    }
}

// ---------------------------------------------------------------------------
// row_fused: wave-per-row scoring + sparse softmax + PV (dual accumulator
// chains + pair prefetch), XCD-pinned batch mapping: xcd = blockIdx.x & 7
// (round-robin dispatch); batch = xcd>>1 so each XCD's 4MB L2 holds exactly
// one batch's K+V slab.
// ---------------------------------------------------------------------------
__global__ __launch_bounds__(256) void row_fused(
    const u16* __restrict__ QKV, const float* __restrict__ vsum,
    const int* __restrict__ row_count, const int2* __restrict__ row_edges,
    u16* __restrict__ Obf)
{
    const int t = threadIdx.x;
    const int wave = t >> 6, lane = t & 63;
    const int gid = blockIdx.x;                 // 0..2047
    const int xcd = gid & 7;
    const int b = xcd >> 1;                     // 2 XCDs per batch
    const int rowgrp = ((xcd & 1) << 8) | (gid >> 3);   // 0..511
    const int row = rowgrp * 4 + wave;
    const int R = b * N_ + row;
    int cnt = row_count[R];
    if (cnt > CAP) cnt = CAP;

    // edge entries register-resident: lane p < cnt holds entry p
    int ej = 0; float ws = 0.f;
    if (lane < cnt) {
        const int2 v = row_edges[(size_t)R * CAP + lane];
        ej = v.x; ws = __int_as_float(v.y);
    }
    // last-e-wins dedup via shfl broadcast (winner = max e per j)
    const int myj = ej >> 16, mye = ej & 0xFFFF;
    bool win = (lane < cnt);
    for (int p = 0; p < cnt; ++p) {
        const int oj = __shfl(ej, p);
        if (win && (oj >> 16) == myj && (oj & 0xFFFF) > mye) win = false;
    }
    unsigned long long m = __ballot(win);

    const char* base = (const char*)QKV;
    const uint4 qv = *(const uint4*)(base + (size_t)R * 3072 + lane * 16);
    const float q0=blo(qv.x), q1=bhi(qv.x), q2=blo(qv.y), q3=bhi(qv.y),
                q4=blo(qv.z), q5=bhi(qv.z), q6=blo(qv.w), q7=bhi(qv.w);
    const float rs = 0.02209708691207961f;   // 1/sqrt(2048)

    float A0=0.f,A1=0.f,A2=0.f,A3=0.f,A4=0.f,A5=0.f,A6=0.f,A7=0.f;
    float B0=0.f,B1=0.f,B2=0.f,B3=0.f,B4=0.f,B5=0.f,B6=0.f,B7=0.f;
    float dsA = 0.f, dsB = 0.f;

#define FETCH(MM, KV1,VV1,W1,KV2,VV2,W2,NN)                                  \
    { int p_ = (int)__ffsll((long long)MM) - 1; MM &= MM - 1;                \
      const int j_ = __shfl(ej, p_) >> 16; W1 = __shfl(ws, p_);              \
      const char* nb_ = base + (size_t)(b * N_ + j_) * 3072;                 \
      KV1 = *(const uint4*)(nb_ + 1024 + lane * 16);                         \
      VV1 = *(const uint4*)(nb_ + 2048 + lane * 16);                         \
      if (MM) {                                                              \
        int q_ = (int)__ffsll((long long)MM) - 1; MM &= MM - 1;              \
        const int j2_ = __shfl(ej, q_) >> 16; W2 = __shfl(ws, q_);           \
        const char* nb2_ = base + (size_t)(b * N_ + j2_) * 3072;             \
        KV2 = *(const uint4*)(nb2_ + 1024 + lane * 16);                      \
        VV2 = *(const uint4*)(nb2_ + 2048 + lane * 16);                      \
        NN = 2;                                                              \
      } else NN = 1; }

#define PROC(kv, vv, wsp, S)                                                 \
    { float s_ = q0*blo(kv.x) + q1*bhi(kv.x) + q2*blo(kv.y) + q3*bhi(kv.y)   \
               + q4*blo(kv.z) + q5*bhi(kv.z) + q6*blo(kv.w) + q7*bhi(kv.w);  \
      s_ += __shfl_xor(s_, 1);                                               \
      s_ += __shfl_xor(s_, 2);                                               \
      s_ += __shfl_xor(s_, 4);                                               \
      s_ += __shfl_xor(s_, 8);                                               \
      const float x_ = __expf(s_ * rs * (wsp)) - 1.f;                        \
      ds##S += x_;                                                           \
      S##0 = fmaf(x_, blo(vv.x), S##0); S##1 = fmaf(x_, bhi(vv.x), S##1);    \
      S##2 = fmaf(x_, blo(vv.y), S##2); S##3 = fmaf(x_, bhi(vv.y), S##3);    \
      S##4 = fmaf(x_, blo(vv.z), S##4); S##5 = fmaf(x_, bhi(vv.z), S##5);    \
      S##6 = fmaf(x_, blo(vv.w), S##6); S##7 = fmaf(x_, bhi(vv.w), S##7); }

    if (m) {
        uint4 kv1, vv1, kv2, vv2; float w1, w2; int n1;
        FETCH(m, kv1, vv1, w1, kv2, vv2, w2, n1);
        while (m) {
            uint4 nk1, nv1, nk2, nv2; float nw1, nw2; int n2;
            FETCH(m, nk1, nv1, nw1, nk2, nv2, nw2, n2);
            PROC(kv1, vv1, w1, A);
            if (n1 == 2) PROC(kv2, vv2, w2, B);
            kv1 = nk1; vv1 = nv1; w1 = nw1;
            kv2 = nk2; vv2 = nv2; w2 = nw2; n1 = n2;
        }
        PROC(kv1, vv1, w1, A);
        if (n1 == 2) PROC(kv2, vv2, w2, B);
    }
#undef FETCH
#undef PROC

    const float inv = 1.0f / (2048.0f + dsA + dsB);
    const float* vsp = vsum + (b * H_ + (lane >> 4)) * 128 + (lane & 15) * 8;
    const float4 vs0 = *(const float4*)vsp;
    const float4 vs1 = *(const float4*)(vsp + 4);
    union { u16 u[8]; uint4 v; } o;
    o.u[0]=f2b((vs0.x+A0+B0)*inv); o.u[1]=f2b((vs0.y+A1+B1)*inv);
    o.u[2]=f2b((vs0.z+A2+B2)*inv); o.u[3]=f2b((vs0.w+A3+B3)*inv);
    o.u[4]=f2b((vs1.x+A4+B4)*inv); o.u[5]=f2b((vs1.y+A5+B5)*inv);
    o.u[6]=f2b((vs1.z+A6+B6)*inv); o.u[7]=f2b((vs1.w+A7+B7)*inv);
    const int ob = ((lane >> 4) << 8) + (((lane & 15) * 16) ^ ((R & 7) << 4));
    *(uint4*)((char*)Obf + (size_t)R * 1024 + ob) = o.v;
}

// ---------------------------------------------------------------------------
// out_mfma: d_out[8192][128] f32 = Obf[8192][512] x OWbf[128][512]^T + out_b
// grid = 256 row-blocks (M-tile 32), 4 waves (2x2), wave tile 16x64.
// ---------------------------------------------------------------------------
__global__ __launch_bounds__(256) void out_mfma(
    const u16* __restrict__ Obf, const u16* __restrict__ OWbf,
    const float* __restrict__ bo, float* __restrict__ Out)
{
    __shared__ u16 As[32 * 128];    // 8KB
    __shared__ u16 Bs[128 * 128];   // 32KB
    const int rb = blockIdx.x;
    const int t = threadIdx.x;
    const int lane = t & 63, wave = t >> 6;
    const int wm = wave >> 1, wn = wave & 1;
    const int l15 = lane & 15, l4 = lane >> 4;

    f32x4 acc[4];
    #pragma unroll
    for (int j = 0; j < 4; ++j) acc[j] = (f32x4){0.f, 0.f, 0.f, 0.f};

    for (int kc = 0; kc < 4; ++kc) {
        #pragma unroll
        for (int q = 0; q < 2; ++q) {       // A: 8KB
            const int o = t * 16 + q * 4096;
            const int arow = o >> 8, ob = o & 255;
            g2l16((const char*)Obf + (size_t)(rb * 32 + arow) * 1024 + kc * 256 + ob,
                  (char*)As + o);
        }
        #pragma unroll
        for (int q = 0; q < 8; ++q) {       // B: 32KB
            const int o = t * 16 + q * 4096;
            const int c = o >> 8, ob = o & 255;
            g2l16((const char*)OWbf + (size_t)c * 1024 + kc * 256 + ob,
                  (char*)Bs + o);
        }
        __syncthreads();
        #pragma unroll
        for (int ks = 0; ks < 4; ++ks) {
            const int kb = ks * 64 + l4 * 16;
            bf16x8 a0, bb[4];
            {
                const int row = wm * 16 + l15;
                a0 = *(const bf16x8*)((const char*)As + row * 256 + (kb ^ ((row & 7) << 4)));
            }
            #pragma unroll
            for (int fn = 0; fn < 4; ++fn) {
                const int col = wn * 64 + fn * 16 + l15;
                bb[fn] = *(const bf16x8*)((const char*)Bs + col * 256 + (kb ^ ((col & 7) << 4)));
            }
            #pragma unroll
            for (int fn = 0; fn < 4; ++fn)
                acc[fn] = __builtin_amdgcn_mfma_f32_16x16x32_bf16(
                    a0, bb[fn], acc[fn], 0, 0, 0);
        }
        __syncthreads();
    }

    #pragma unroll
    for (int fn = 0; fn < 4; ++fn) {
        const int col = wn * 64 + fn * 16 + l15;
        const float bv = bo[col];
        #pragma unroll
        for (int r = 0; r < 4; ++r) {
            const int row = rb * 32 + wm * 16 + l4 * 4 + r;
            Out[(size_t)row * OUT_ + col] = acc[fn][r] + bv;
        }
    }
}

// ---------------------------------------------------------------------------
extern "C" void kernel_launch(void* const* d_in, const int* in_sizes, int n_in,
                              void* d_out, int out_size, void* d_ws, size_t ws_size,
                              hipStream_t stream)
{
    const float* x     = (const float*)d_in[0];
    const int*   nidx  = (const int*)  d_in[1];
    const float* attr  = (const float*)d_in[2];
    const float* wq_w  = (const float*)d_in[3];
    const float* wq_b  = (const float*)d_in[4];
    const float* wk_w  = (const float*)d_in[5];
    const float* wk_b  = (const float*)d_in[6];
    const float* wv_w  = (const float*)d_in[7];
    const float* wv_b  = (const float*)d_in[8];
    const float* out_w = (const float*)d_in[9];
    const float* out_b = (const float*)d_in[10];
    float* out = (float*)d_out;

    char* ws = (char*)d_ws;
    size_t off = 0;
    auto alloc = [&](size_t bytes) -> char* {
        char* p = ws + off;
        off += (bytes + 255) & ~(size_t)255;
        return p;
    };
    u16*  Xbf  = (u16*)alloc((size_t)M_ * D_ * 2);          // 2MB
    u16*  Wbf  = (u16*)alloc((size_t)12 * D_ * D_ * 2);     // 384KB
    float* biasf = (float*)alloc((size_t)12 * D_ * 4);      // 6KB
    u16*  QKV  = (u16*)alloc((size_t)M_ * C3_ * 2);         // 24MB
    u16*  OWbf = (u16*)alloc((size_t)OUT_ * HD_ * 2);       // 128KB
    u16*  Obf  = (u16*)alloc((size_t)M_ * HD_ * 2);         // 8MB
    float* vsum = (float*)alloc((size_t)B_ * H_ * D_ * 4);  // 8KB
    int*  row_count = (int*)alloc((size_t)B_ * N_ * 4);     // 32KB
    int2* row_edges = (int2*)alloc((size_t)B_ * N_ * CAP * 8);

    prep_kernel<<<641, 256, 0, stream>>>(
        x, wq_w, wk_w, wv_w, wq_b, wk_b, wv_b, out_w,
        Xbf, Wbf, biasf, OWbf, row_count, vsum);
    qkv_append<<<768 + 4096, 256, 0, stream>>>(
        Xbf, Wbf, biasf, nidx, attr, QKV, vsum, row_count, row_edges);
    row_fused<<<2048, 256, 0, stream>>>(
        QKV, vsum, row_count, row_edges, Obf);
    out_mfma<<<M_ / 32, 256, 0, stream>>>(Obf, OWbf, out_b, out);
}

// Round 12
// 73.361 us; speedup vs baseline: 1.2329x; 1.0349x over previous
//
#include <hip/hip_runtime.h>
#include <hip/hip_bf16.h>
#include <math.h>

// Problem constants
constexpr int B_ = 4;
constexpr int N_ = 2048;
constexpr int D_ = 128;
constexpr int H_ = 4;
constexpr int E_ = 32768;
constexpr int W_ = 8;
constexpr int OUT_ = 128;
constexpr int HD_ = H_ * D_;    // 512
constexpr int C3_ = 3 * HD_;    // 1536 combined QKV cols
constexpr int CAP = 64;         // max edges per row bucket (Poisson(16))
constexpr int M_ = B_ * N_;     // 8192 rows

typedef __attribute__((ext_vector_type(8))) __bf16 bf16x8;
typedef __attribute__((ext_vector_type(4))) float f32x4;
typedef unsigned int uint32;
typedef unsigned short u16;

__device__ __forceinline__ u16 f2b(float f) {
    __hip_bfloat16 h = __float2bfloat16(f);
    return *(u16*)&h;
}
__device__ __forceinline__ float blo(uint32 u) { return __uint_as_float(u << 16); }
__device__ __forceinline__ float bhi(uint32 u) { return __uint_as_float(u & 0xffff0000u); }

// async 16B global->LDS copy (dest = wave-uniform base + lane*16)
__device__ __forceinline__ void g2l16(const void* g, void* l) {
    __builtin_amdgcn_global_load_lds(
        (const __attribute__((address_space(1))) unsigned int*)(uintptr_t)g,
        (__attribute__((address_space(3))) unsigned int*)(uintptr_t)l,
        16, 0, 0);
}

// ---------------------------------------------------------------------------
// K1 prep_append: NO LDS -> full occupancy for latency-bound work.
// [0,512):    cast x -> Xbf, bf16 SWIZZLED within each 256B row (for g2l16)
// [512,608):  cast 12 weight mats -> Wbf (swizzled) + biasf
// [608,640):  cast out_w -> OWbf (swizzled)
// [640,4736): edge append, 8 edges/wave, fully parallel
// row_count/vsum zeroed by preceding hipMemsetAsync.
// ---------------------------------------------------------------------------
__global__ __launch_bounds__(256) void prep_append(
    const float* __restrict__ X,
    const float* __restrict__ wq, const float* __restrict__ wk, const float* __restrict__ wv,
    const float* __restrict__ bq, const float* __restrict__ bk, const float* __restrict__ bv,
    const float* __restrict__ OW,
    const int* __restrict__ nidx, const float* __restrict__ attr,
    u16* __restrict__ Xbf, u16* __restrict__ Wbf, float* __restrict__ biasf,
    u16* __restrict__ OWbf,
    int* __restrict__ row_count, int2* __restrict__ row_edges)
{
    const int blk = blockIdx.x;
    const int t = threadIdx.x;
    if (blk < 512) {                       // ---- cast_x (swizzled) ----
        const int tid = blk * 256 + t;
        const int row = tid >> 4, sub = tid & 15;
        const float4 f0 = *(const float4*)(X + (size_t)row * 128 + sub * 8);
        const float4 f1 = *(const float4*)(X + (size_t)row * 128 + sub * 8 + 4);
        union { u16 u[8]; uint4 v; } pk;
        pk.u[0]=f2b(f0.x); pk.u[1]=f2b(f0.y); pk.u[2]=f2b(f0.z); pk.u[3]=f2b(f0.w);
        pk.u[4]=f2b(f1.x); pk.u[5]=f2b(f1.y); pk.u[6]=f2b(f1.z); pk.u[7]=f2b(f1.w);
        const int ob = row * 256 + ((sub * 16) ^ ((row & 7) << 4));
        *(uint4*)((char*)Xbf + ob) = pk.v;
    } else if (blk < 608) {                // ---- cast_w (swizzled) + bias ----
        const int c = (blk - 512) * 256 + t;   // 0..24575
        const int g = c >> 11, idx = c & 2047;
        const int t3 = g >> 2, h = g & 3;
        const float* Wsrc = (t3 == 0 ? wq : t3 == 1 ? wk : wv) + (size_t)h * 128 * 128;
        const int e = idx >> 4, sub = idx & 15;
        const float4 f0 = *(const float4*)(Wsrc + (size_t)e * 128 + sub * 8);
        const float4 f1 = *(const float4*)(Wsrc + (size_t)e * 128 + sub * 8 + 4);
        union { u16 u[8]; uint4 v; } pk;
        pk.u[0]=f2b(f0.x); pk.u[1]=f2b(f0.y); pk.u[2]=f2b(f0.z); pk.u[3]=f2b(f0.w);
        pk.u[4]=f2b(f1.x); pk.u[5]=f2b(f1.y); pk.u[6]=f2b(f1.z); pk.u[7]=f2b(f1.w);
        const int ob = g * 32768 + e * 256 + ((sub * 16) ^ ((e & 7) << 4));
        *(uint4*)((char*)Wbf + ob) = pk.v;
        if (idx < 128) {
            const float* Bsrc = (t3 == 0 ? bq : t3 == 1 ? bk : bv) + h * 128;
            biasf[g * 128 + idx] = Bsrc[idx];
        }
    } else if (blk < 640) {                // ---- cast_ow (swizzled) ----
        const int tid = (blk - 608) * 256 + t;  // 0..8191
        const int c = tid >> 6, sub = tid & 63;
        const float4 f0 = *(const float4*)(OW + (size_t)c * 512 + sub * 8);
        const float4 f1 = *(const float4*)(OW + (size_t)c * 512 + sub * 8 + 4);
        union { u16 u[8]; uint4 v; } pk;
        pk.u[0]=f2b(f0.x); pk.u[1]=f2b(f0.y); pk.u[2]=f2b(f0.z); pk.u[3]=f2b(f0.w);
        pk.u[4]=f2b(f1.x); pk.u[5]=f2b(f1.y); pk.u[6]=f2b(f1.z); pk.u[7]=f2b(f1.w);
        const int ob = c * 1024 + ((sub * 16) ^ ((c & 7) << 4));
        *(uint4*)((char*)OWbf + ob) = pk.v;
    } else {                               // ---- append ----
        const int wave = t >> 6, lane = t & 63;
        const int gw = (blk - 640) * 4 + wave;    // 0..16383
        const int e0g = gw * 8;
        const int b = e0g / E_;
        const int e0 = e0g % E_;
        float a = attr[((size_t)b * E_ + e0) * W_ + lane];
        a += __shfl_xor(a, 1);
        a += __shfl_xor(a, 2);
        a += __shfl_xor(a, 4);
        if ((lane & 7) == 0) {
            const int sub = lane >> 3;
            const int e = e0 + sub;
            const int i = nidx[b * 2 * E_ + e];
            const int j = nidx[b * 2 * E_ + E_ + e];
            const int pos = atomicAdd(&row_count[b * N_ + i], 1);
            if (pos < CAP)
                row_edges[(size_t)(b * N_ + i) * CAP + pos] =
                    make_int2(e | (j << 16), __float_as_int(a));
        }
    }
}

// ---------------------------------------------------------------------------
// K2 qkv_gemm: QKV[8192][1536] bf16 = Xbf x Wbf^T + bias.  768 blocks.
// A/B tiles staged via async global_load_lds (16B/lane, deep queue — the
// proven fast path); fragments read from LDS with XOR-swizzle (conflict-free).
// Epilogue repacks C through As (reused) for coalesced uint4 stores.
// V col-blocks (g>=8) also column-reduce into vsum.
// ---------------------------------------------------------------------------
__global__ __launch_bounds__(256) void qkv_gemm(
    const u16* __restrict__ Xbf, const u16* __restrict__ Wbf,
    const float* __restrict__ biasf, u16* __restrict__ QKV,
    float* __restrict__ vsum)
{
    __shared__ u16 As[128 * 128];   // 32KB
    __shared__ u16 Bs[128 * 128];   // 32KB
    const int t = threadIdx.x;
    const int lane = t & 63, wave = t >> 6;
    const int rb = blockIdx.x & 63;
    const int g  = blockIdx.x >> 6;
    const int wm = wave >> 1, wn = wave & 1;
    const int l15 = lane & 15, l4 = lane >> 4;

    const char* Asrc = (const char*)(Xbf + (size_t)rb * 128 * 128);
    const char* Bsrc = (const char*)(Wbf + (size_t)g  * 128 * 128);
    #pragma unroll
    for (int q = 0; q < 8; ++q) {
        const int o = t * 16 + q * 4096;
        g2l16(Asrc + o, (char*)As + o);
        g2l16(Bsrc + o, (char*)Bs + o);
    }
    __syncthreads();

    f32x4 acc[4][4];
    #pragma unroll
    for (int i = 0; i < 4; ++i)
        #pragma unroll
        for (int j = 0; j < 4; ++j) acc[i][j] = (f32x4){0.f, 0.f, 0.f, 0.f};

    #pragma unroll
    for (int ks = 0; ks < 4; ++ks) {
        const int kb = ks * 64 + l4 * 16;
        bf16x8 a[4], bb[4];
        #pragma unroll
        for (int fm = 0; fm < 4; ++fm) {
            const int row = wm * 64 + fm * 16 + l15;
            a[fm] = *(const bf16x8*)((const char*)As + row * 256 + (kb ^ ((row & 7) << 4)));
        }
        #pragma unroll
        for (int fn = 0; fn < 4; ++fn) {
            const int col = wn * 64 + fn * 16 + l15;
            bb[fn] = *(const bf16x8*)((const char*)Bs + col * 256 + (kb ^ ((col & 7) << 4)));
        }
        #pragma unroll
        for (int fm = 0; fm < 4; ++fm)
            #pragma unroll
            for (int fn = 0; fn < 4; ++fn)
                acc[fm][fn] = __builtin_amdgcn_mfma_f32_16x16x32_bf16(
                    a[fm], bb[fn], acc[fm][fn], 0, 0, 0);
    }

    __syncthreads();   // all reads of As done; reuse As for C repack

    #pragma unroll
    for (int fm = 0; fm < 4; ++fm)
        #pragma unroll
        for (int fn = 0; fn < 4; ++fn) {
            const int col = wn * 64 + fn * 16 + l15;
            const float bv = biasf[g * 128 + col];
            #pragma unroll
            for (int r = 0; r < 4; ++r) {
                const int row = wm * 64 + fm * 16 + l4 * 4 + r;
                *(u16*)((char*)As + row * 256 + ((col * 2) ^ ((row & 7) << 4))) =
                    f2b(acc[fm][fn][r] + bv);
            }
        }

    if (g >= 8) {   // fused V column-sum (includes bias via +64*bv per wave)
        const int h = g - 8;
        const int b = rb >> 4;      // 16 row-blocks per batch
        #pragma unroll
        for (int fn = 0; fn < 4; ++fn) {
            float s = 0.f;
            #pragma unroll
            for (int fm = 0; fm < 4; ++fm)
                #pragma unroll
                for (int r = 0; r < 4; ++r) s += acc[fm][fn][r];
            s += __shfl_xor(s, 16);
            s += __shfl_xor(s, 32);
            if (l4 == 0) {
                const int col = wn * 64 + fn * 16 + l15;
                const float bv = biasf[g * 128 + col];
                atomicAdd(&vsum[(b * H_ + h) * 128 + col], s + 64.f * bv);
            }
        }
    }
    __syncthreads();

    // coalesced store: 8 x uint4 per thread
    #pragma unroll
    for (int q = 0; q < 8; ++q) {
        const int idx = t + q * 256;          // chunk 0..2047
        const int row = idx >> 4, c = idx & 15;
        const uint4 v = *(const uint4*)((char*)As + row * 256 + ((c * 16) ^ ((row & 7) << 4)));
        *(uint4*)(QKV + (size_t)(rb * 128 + row) * C3_ + g * 128 + c * 8) = v;
    }
}

// ---------------------------------------------------------------------------
// row_fused: wave-per-row scoring + sparse softmax + PV (dual accumulator
// chains + pair prefetch), XCD-pinned batch mapping: xcd = blockIdx.x & 7
// (round-robin dispatch); batch = xcd>>1 so each XCD's 4MB L2 holds exactly
// one batch's K+V slab.
// ---------------------------------------------------------------------------
__global__ __launch_bounds__(256) void row_fused(
    const u16* __restrict__ QKV, const float* __restrict__ vsum,
    const int* __restrict__ row_count, const int2* __restrict__ row_edges,
    u16* __restrict__ Obf)
{
    const int t = threadIdx.x;
    const int wave = t >> 6, lane = t & 63;
    const int gid = blockIdx.x;                 // 0..2047
    const int xcd = gid & 7;
    const int b = xcd >> 1;                     // 2 XCDs per batch
    const int rowgrp = ((xcd & 1) << 8) | (gid >> 3);   // 0..511
    const int row = rowgrp * 4 + wave;
    const int R = b * N_ + row;
    int cnt = row_count[R];
    if (cnt > CAP) cnt = CAP;

    // edge entries register-resident: lane p < cnt holds entry p
    int ej = 0; float ws = 0.f;
    if (lane < cnt) {
        const int2 v = row_edges[(size_t)R * CAP + lane];
        ej = v.x; ws = __int_as_float(v.y);
    }
    // last-e-wins dedup via shfl broadcast (winner = max e per j)
    const int myj = ej >> 16, mye = ej & 0xFFFF;
    bool win = (lane < cnt);
    for (int p = 0; p < cnt; ++p) {
        const int oj = __shfl(ej, p);
        if (win && (oj >> 16) == myj && (oj & 0xFFFF) > mye) win = false;
    }
    unsigned long long m = __ballot(win);

    const char* base = (const char*)QKV;
    const uint4 qv = *(const uint4*)(base + (size_t)R * 3072 + lane * 16);
    const float q0=blo(qv.x), q1=bhi(qv.x), q2=blo(qv.y), q3=bhi(qv.y),
                q4=blo(qv.z), q5=bhi(qv.z), q6=blo(qv.w), q7=bhi(qv.w);
    const float rs = 0.02209708691207961f;   // 1/sqrt(2048)

    float A0=0.f,A1=0.f,A2=0.f,A3=0.f,A4=0.f,A5=0.f,A6=0.f,A7=0.f;
    float B0=0.f,B1=0.f,B2=0.f,B3=0.f,B4=0.f,B5=0.f,B6=0.f,B7=0.f;
    float dsA = 0.f, dsB = 0.f;

#define FETCH(MM, KV1,VV1,W1,KV2,VV2,W2,NN)                                  \
    { int p_ = (int)__ffsll((long long)MM) - 1; MM &= MM - 1;                \
      const int j_ = __shfl(ej, p_) >> 16; W1 = __shfl(ws, p_);              \
      const char* nb_ = base + (size_t)(b * N_ + j_) * 3072;                 \
      KV1 = *(const uint4*)(nb_ + 1024 + lane * 16);                         \
      VV1 = *(const uint4*)(nb_ + 2048 + lane * 16);                         \
      if (MM) {                                                              \
        int q_ = (int)__ffsll((long long)MM) - 1; MM &= MM - 1;              \
        const int j2_ = __shfl(ej, q_) >> 16; W2 = __shfl(ws, q_);           \
        const char* nb2_ = base + (size_t)(b * N_ + j2_) * 3072;             \
        KV2 = *(const uint4*)(nb2_ + 1024 + lane * 16);                      \
        VV2 = *(const uint4*)(nb2_ + 2048 + lane * 16);                      \
        NN = 2;                                                              \
      } else NN = 1; }

#define PROC(kv, vv, wsp, S)                                                 \
    { float s_ = q0*blo(kv.x) + q1*bhi(kv.x) + q2*blo(kv.y) + q3*bhi(kv.y)   \
               + q4*blo(kv.z) + q5*bhi(kv.z) + q6*blo(kv.w) + q7*bhi(kv.w);  \
      s_ += __shfl_xor(s_, 1);                                               \
      s_ += __shfl_xor(s_, 2);                                               \
      s_ += __shfl_xor(s_, 4);                                               \
      s_ += __shfl_xor(s_, 8);                                               \
      const float x_ = __expf(s_ * rs * (wsp)) - 1.f;                        \
      ds##S += x_;                                                           \
      S##0 = fmaf(x_, blo(vv.x), S##0); S##1 = fmaf(x_, bhi(vv.x), S##1);    \
      S##2 = fmaf(x_, blo(vv.y), S##2); S##3 = fmaf(x_, bhi(vv.y), S##3);    \
      S##4 = fmaf(x_, blo(vv.z), S##4); S##5 = fmaf(x_, bhi(vv.z), S##5);    \
      S##6 = fmaf(x_, blo(vv.w), S##6); S##7 = fmaf(x_, bhi(vv.w), S##7); }

    if (m) {
        uint4 kv1, vv1, kv2, vv2; float w1, w2; int n1;
        FETCH(m, kv1, vv1, w1, kv2, vv2, w2, n1);
        while (m) {
            uint4 nk1, nv1, nk2, nv2; float nw1, nw2; int n2;
            FETCH(m, nk1, nv1, nw1, nk2, nv2, nw2, n2);
            PROC(kv1, vv1, w1, A);
            if (n1 == 2) PROC(kv2, vv2, w2, B);
            kv1 = nk1; vv1 = nv1; w1 = nw1;
            kv2 = nk2; vv2 = nv2; w2 = nw2; n1 = n2;
        }
        PROC(kv1, vv1, w1, A);
        if (n1 == 2) PROC(kv2, vv2, w2, B);
    }
#undef FETCH
#undef PROC

    const float inv = 1.0f / (2048.0f + dsA + dsB);
    const float* vsp = vsum + (b * H_ + (lane >> 4)) * 128 + (lane & 15) * 8;
    const float4 vs0 = *(const float4*)vsp;
    const float4 vs1 = *(const float4*)(vsp + 4);
    union { u16 u[8]; uint4 v; } o;
    o.u[0]=f2b((vs0.x+A0+B0)*inv); o.u[1]=f2b((vs0.y+A1+B1)*inv);
    o.u[2]=f2b((vs0.z+A2+B2)*inv); o.u[3]=f2b((vs0.w+A3+B3)*inv);
    o.u[4]=f2b((vs1.x+A4+B4)*inv); o.u[5]=f2b((vs1.y+A5+B5)*inv);
    o.u[6]=f2b((vs1.z+A6+B6)*inv); o.u[7]=f2b((vs1.w+A7+B7)*inv);
    const int ob = ((lane >> 4) << 8) + (((lane & 15) * 16) ^ ((R & 7) << 4));
    *(uint4*)((char*)Obf + (size_t)R * 1024 + ob) = o.v;
}

// ---------------------------------------------------------------------------
// out_mfma: d_out[8192][128] f32 = Obf[8192][512] x OWbf[128][512]^T + out_b
// grid = 256 row-blocks (M-tile 32), 4 waves (2x2), wave tile 16x64.
// ---------------------------------------------------------------------------
__global__ __launch_bounds__(256) void out_mfma(
    const u16* __restrict__ Obf, const u16* __restrict__ OWbf,
    const float* __restrict__ bo, float* __restrict__ Out)
{
    __shared__ u16 As[32 * 128];    // 8KB
    __shared__ u16 Bs[128 * 128];   // 32KB
    const int rb = blockIdx.x;
    const int t = threadIdx.x;
    const int lane = t & 63, wave = t >> 6;
    const int wm = wave >> 1, wn = wave & 1;
    const int l15 = lane & 15, l4 = lane >> 4;

    f32x4 acc[4];
    #pragma unroll
    for (int j = 0; j < 4; ++j) acc[j] = (f32x4){0.f, 0.f, 0.f, 0.f};

    for (int kc = 0; kc < 4; ++kc) {
        #pragma unroll
        for (int q = 0; q < 2; ++q) {       // A: 8KB
            const int o = t * 16 + q * 4096;
            const int arow = o >> 8, ob = o & 255;
            g2l16((const char*)Obf + (size_t)(rb * 32 + arow) * 1024 + kc * 256 + ob,
                  (char*)As + o);
        }
        #pragma unroll
        for (int q = 0; q < 8; ++q) {       // B: 32KB
            const int o = t * 16 + q * 4096;
            const int c = o >> 8, ob = o & 255;
            g2l16((const char*)OWbf + (size_t)c * 1024 + kc * 256 + ob,
                  (char*)Bs + o);
        }
        __syncthreads();
        #pragma unroll
        for (int ks = 0; ks < 4; ++ks) {
            const int kb = ks * 64 + l4 * 16;
            bf16x8 a0, bb[4];
            {
                const int row = wm * 16 + l15;
                a0 = *(const bf16x8*)((const char*)As + row * 256 + (kb ^ ((row & 7) << 4)));
            }
            #pragma unroll
            for (int fn = 0; fn < 4; ++fn) {
                const int col = wn * 64 + fn * 16 + l15;
                bb[fn] = *(const bf16x8*)((const char*)Bs + col * 256 + (kb ^ ((col & 7) << 4)));
            }
            #pragma unroll
            for (int fn = 0; fn < 4; ++fn)
                acc[fn] = __builtin_amdgcn_mfma_f32_16x16x32_bf16(
                    a0, bb[fn], acc[fn], 0, 0, 0);
        }
        __syncthreads();
    }

    #pragma unroll
    for (int fn = 0; fn < 4; ++fn) {
        const int col = wn * 64 + fn * 16 + l15;
        const float bv = bo[col];
        #pragma unroll
        for (int r = 0; r < 4; ++r) {
            const int row = rb * 32 + wm * 16 + l4 * 4 + r;
            Out[(size_t)row * OUT_ + col] = acc[fn][r] + bv;
        }
    }
}

// ---------------------------------------------------------------------------
extern "C" void kernel_launch(void* const* d_in, const int* in_sizes, int n_in,
                              void* d_out, int out_size, void* d_ws, size_t ws_size,
                              hipStream_t stream)
{
    const float* x     = (const float*)d_in[0];
    const int*   nidx  = (const int*)  d_in[1];
    const float* attr  = (const float*)d_in[2];
    const float* wq_w  = (const float*)d_in[3];
    const float* wq_b  = (const float*)d_in[4];
    const float* wk_w  = (const float*)d_in[5];
    const float* wk_b  = (const float*)d_in[6];
    const float* wv_w  = (const float*)d_in[7];
    const float* wv_b  = (const float*)d_in[8];
    const float* out_w = (const float*)d_in[9];
    const float* out_b = (const float*)d_in[10];
    float* out = (float*)d_out;

    char* ws = (char*)d_ws;
    size_t off = 0;
    auto alloc = [&](size_t bytes) -> char* {
        char* p = ws + off;
        off += (bytes + 255) & ~(size_t)255;
        return p;
    };
    u16*  Xbf  = (u16*)alloc((size_t)M_ * D_ * 2);          // 2MB
    u16*  Wbf  = (u16*)alloc((size_t)12 * D_ * D_ * 2);     // 384KB
    float* biasf = (float*)alloc((size_t)12 * D_ * 4);      // 6KB
    u16*  QKV  = (u16*)alloc((size_t)M_ * C3_ * 2);         // 24MB
    u16*  OWbf = (u16*)alloc((size_t)OUT_ * HD_ * 2);       // 128KB
    u16*  Obf  = (u16*)alloc((size_t)M_ * HD_ * 2);         // 8MB
    float* vsum = (float*)alloc((size_t)B_ * H_ * D_ * 4);  // 8KB
    int*  row_count = (int*)alloc((size_t)B_ * N_ * 4);     // 32KB (contiguous after vsum)
    int2* row_edges = (int2*)alloc((size_t)B_ * N_ * CAP * 8);

    // vsum + row_count are contiguous: one 40KB zero-fill
    hipMemsetAsync(vsum, 0, (size_t)B_ * H_ * D_ * 4 + (size_t)B_ * N_ * 4, stream);

    prep_append<<<640 + 4096, 256, 0, stream>>>(
        x, wq_w, wk_w, wv_w, wq_b, wk_b, wv_b, out_w, nidx, attr,
        Xbf, Wbf, biasf, OWbf, row_count, row_edges);
    qkv_gemm<<<768, 256, 0, stream>>>(Xbf, Wbf, biasf, QKV, vsum);
    row_fused<<<2048, 256, 0, stream>>>(
        QKV, vsum, row_count, row_edges, Obf);
    out_mfma<<<M_ / 32, 256, 0, stream>>>(Obf, OWbf, out_b, out);
}